// Round 3
// baseline (854.810 us; speedup 1.0000x reference)
//
#include <hip/hip_runtime.h>
#include <stdint.h>

typedef unsigned short u16;
typedef u16 u16x8 __attribute__((ext_vector_type(8)));
typedef __bf16 bf16x8 __attribute__((ext_vector_type(8)));
typedef float f32x4 __attribute__((ext_vector_type(4)));

__device__ __forceinline__ float b2f(u16 u) {
    union { unsigned int i; float f; } c; c.i = ((unsigned int)u) << 16; return c.f;
}
__device__ __forceinline__ u16 f2b(float f) {  // round-to-nearest-even
    unsigned int u = __float_as_uint(f);
    u += 0x7fff + ((u >> 16) & 1);
    return (u16)(u >> 16);
}

// ---------------------------------------------------------------------------
// Per-wave dtype detect from mask (values are exactly {0.0,1.0}).
// f32 storage: every even u16 (low half of f32) is 0. bf16 storage: even u16s
// are elements 0,2,..,126 -> ~half are 0x3F80. All waves sample the SAME 64
// u16s -> result is uniform across the grid. P(miss | bf16) = 2^-64.
// ---------------------------------------------------------------------------
__device__ __forceinline__ int detect_dt(const u16* __restrict__ m) {
    unsigned long long b = __ballot(m[2 * (threadIdx.x & 63)] != 0);
    return b != 0ull ? 1 : 0;
}

// runtime-dtype scalar param read
__device__ __forceinline__ float cv(const void* p, int j, int dt) {
    return dt ? b2f(((const u16*)p)[j]) : ((const float*)p)[j];
}

// ---------------------------------------------------------------------------
// Transpose with zero-pad: out[c][r] = (r<R && c<C) ? in[r][c] : 0, r in [0,ldo)
// ---------------------------------------------------------------------------
__device__ void transpose_dev(const void* __restrict__ vin, u16* __restrict__ out,
                              int dt, int R, int C, int ldi, int ldo,
                              int bx, int by) {
    __shared__ __align__(16) u16 tile[64][72];
    const int rt = bx * 64;
    const int ct = by * 64;
    const int t = threadIdx.x;
    const int lr = t >> 2;
    const int lc = (t & 3) * 16;
    const int r = rt + lr;
    if (r < R && (ct + lc + 15) < C) {
        if (dt == 1) {
            const u16* p = (const u16*)vin + (long)r * ldi + ct + lc;
            *(u16x8*)&tile[lr][lc]     = *(const u16x8*)p;
            *(u16x8*)&tile[lr][lc + 8] = *(const u16x8*)(p + 8);
        } else {
            const float* p = (const float*)vin + (long)r * ldi + ct + lc;
            #pragma unroll
            for (int q = 0; q < 4; ++q) {
                f32x4 v4 = *(const f32x4*)(p + q * 4);
                #pragma unroll
                for (int j = 0; j < 4; ++j) tile[lr][lc + q * 4 + j] = f2b(v4[j]);
            }
        }
    } else {
        #pragma unroll
        for (int j = 0; j < 16; ++j) {
            int c = ct + lc + j;
            u16 v = 0;
            if (r < R && c < C)
                v = (dt == 1) ? ((const u16*)vin)[(long)r * ldi + c]
                              : f2b(((const float*)vin)[(long)r * ldi + c]);
            tile[lr][lc + j] = v;
        }
    }
    __syncthreads();
    const int oc = ct + lr;
    if (oc >= C) return;
    u16x8 w0, w1;
    #pragma unroll
    for (int j = 0; j < 8; ++j) w0[j] = tile[lc + j][lr];
    #pragma unroll
    for (int j = 0; j < 8; ++j) w1[j] = tile[lc + 8 + j][lr];
    long ob = (long)oc * ldo + rt + lc;
    if (rt + lc + 15 < ldo) {
        *(u16x8*)(out + ob)     = w0;
        *(u16x8*)(out + ob + 8) = w1;
    } else {
        #pragma unroll
        for (int j = 0; j < 16; ++j) {
            int orr = rt + lc + j;
            if (orr < ldo) out[(long)oc * ldo + orr] = (j < 8) ? w0[j] : w1[j - 8];
        }
    }
}

// ---------------------------------------------------------------------------
// prep mega-kernel: all setup work in ONE dispatch (sections independent;
// dtype derived per-wave, no cross-kernel flag dependency).
//   [0,1256)      W1 [10000,512] -> W1T [512][10016] (zero-pad K)
//   [1256,2512)   W3 [512,10000] -> W3T [10000][512]
//   [2512,2576)   W2 [512,512]   -> W2T [512][512]
//   [2576,2620)   bias canon -> f32: b1[0,512) b2[512,1024) b3[1024,11024)
//   [2620,2636)   ENet LUT (reads E-params directly, dt-converted)
//   [2636,14924)  x f32 -> xb bf16 [4096][10016] zero-padded (dt==0 only)
// ---------------------------------------------------------------------------
__global__ __launch_bounds__(256) void prep(
        const void* __restrict__ x, const void* __restrict__ mask,
        const void* __restrict__ W1, const void* __restrict__ W2,
        const void* __restrict__ W3,
        const void* __restrict__ b1, const void* __restrict__ b2,
        const void* __restrict__ b3,
        const void* __restrict__ E1w, const void* __restrict__ E1b,
        const void* __restrict__ E2w, const void* __restrict__ E2b,
        const void* __restrict__ E3w, const void* __restrict__ E3b,
        u16* __restrict__ W1T, u16* __restrict__ W2T, u16* __restrict__ W3T,
        u16* __restrict__ xb, float* __restrict__ canon,
        float* __restrict__ elut) {
    const int dt = detect_dt((const u16*)mask);
    const int tid = threadIdx.x;
    int bid = blockIdx.x;

    if (bid < 1256) {            // W1T
        transpose_dev(W1, W1T, dt, 10000, 512, 512, 10016, bid >> 3, bid & 7);
        return;
    }
    bid -= 1256;
    if (bid < 1256) {            // W3T
        transpose_dev(W3, W3T, dt, 512, 10000, 10000, 512, bid & 7, bid >> 3);
        return;
    }
    bid -= 1256;
    if (bid < 64) {              // W2T
        transpose_dev(W2, W2T, dt, 512, 512, 512, 512, bid >> 3, bid & 7);
        return;
    }
    bid -= 64;
    if (bid < 44) {              // bias canon
        int i = bid * 256 + tid;
        if (i < 512)        canon[i] = cv(b1, i, dt);
        else if (i < 1024)  canon[i] = cv(b2, i - 512, dt);
        else if (i < 11024) canon[i] = cv(b3, i - 1024, dt);
        return;
    }
    bid -= 44;
    if (bid < 16) {              // ENet LUT: lut[i] = e(-16 + i/128)
        int i = bid * 256 + tid;
        float v = -16.f + (float)i * (1.f / 128.f);
        float e1[16];
        #pragma unroll
        for (int j = 0; j < 16; ++j)
            e1[j] = tanhf(v * cv(E1w, j, dt) + cv(E1b, j, dt));
        float e = cv(E3b, 0, dt);
        #pragma unroll
        for (int k = 0; k < 16; ++k) {
            float s = cv(E2b, k, dt);
            #pragma unroll
            for (int j = 0; j < 16; ++j) s += e1[j] * cv(E2w, j * 16 + k, dt);
            e += tanhf(s) * cv(E3w, k, dt);
        }
        elut[i] = e;
        return;
    }
    bid -= 16;
    // x convert: 4096 rows x 626 16-col chunks; chunk 625 = pure zero pad.
    if (dt != 0) return;
    const int cb = bid % 3;
    const int row = bid / 3;
    const int chunk = cb * 256 + tid;
    if (chunk >= 626) return;
    const int col = chunk * 16;
    u16x8 w0, w1;
    if (col >= 10000) {
        #pragma unroll
        for (int j = 0; j < 8; ++j) { w0[j] = 0; w1[j] = 0; }
    } else {
        const float* p = (const float*)x + (long)row * 10000 + col;
        f32x4 a = *(const f32x4*)(p);
        f32x4 b = *(const f32x4*)(p + 4);
        f32x4 c = *(const f32x4*)(p + 8);
        f32x4 d = *(const f32x4*)(p + 12);
        #pragma unroll
        for (int j = 0; j < 4; ++j) {
            w0[j] = f2b(a[j]); w0[4 + j] = f2b(b[j]);
            w1[j] = f2b(c[j]); w1[4 + j] = f2b(d[j]);
        }
    }
    u16* q = xb + (long)row * 10016 + col;
    *(u16x8*)q = w0;
    *(u16x8*)(q + 8) = w1;
}

// ---------------------------------------------------------------------------
// Direct-load MFMA GEMM: C[M,N] = A[M,K] * Bt[N,K]^T. 128x128 tile, 4 waves.
// NO LDS staging, NO barriers in the K-loop: each wave loads its MFMA
// fragments straight from global (16 rows x 64B contiguous segments per
// load instruction; B panels are <=10MB -> L2-resident; within-block A/B
// redundancy (2 waves) is served by L1). Total MFMA work here is ~5us per
// GEMM -- these kernels are latency/streaming-bound, so maximal scheduling
// freedom + 16 waves/CU beats LDS pipelines.
// A is ALWAYS bf16 (x pre-converted to padded xb when dt==0).
//   MODE 0: h2 = tanh(acc+bias)            (gemm2)
//   MODE 1: fused ENet-LUT + 0.8v residual + mask select, runtime out dtype
//   MODE 2: split-K raw f32 partials       (gemm1)
// A0/K0 = dt==0 variant, A1/K1 = dt==1 variant (identical for MODE 0/1).
// ldA == K in all cases (contiguous row-major).
// ---------------------------------------------------------------------------
template<int MODE>
__global__ __launch_bounds__(256, 4) void gemm_bt(
        const u16* __restrict__ A0, const u16* __restrict__ A1,
        const u16* __restrict__ Bt, const float* __restrict__ biasf,
        void* __restrict__ Cb, float* __restrict__ Cf,
        const void* __restrict__ mask, const float* __restrict__ lut,
        int M, int N, int K0, int K1, int kchunk, int ldB, int ldC) {
    const int dt = (MODE == 0) ? 1 : detect_dt((const u16*)mask);
    const int K = dt ? K1 : K0;
    const u16* __restrict__ Au = dt ? A1 : A0;
    const int ldA = K;

    __shared__ __align__(16) float lutS[(MODE == 1) ? 4096 : 4];

    const int tid = threadIdx.x;
    const int m0 = blockIdx.x * 128;
    const int n0 = blockIdx.y * 128;
    const int lane = tid & 63;
    const int w = tid >> 6;
    const int wm = (w >> 1) * 64;
    const int wn = (w & 1) * 64;
    const int lm = lane & 15;
    const int lq = lane >> 4;

    if (MODE == 1) {
        const f32x4* s = (const f32x4*)lut;
        f32x4* d = (f32x4*)lutS;
        #pragma unroll
        for (int i = 0; i < 4; ++i) d[tid + 256 * i] = s[tid + 256 * i];
        __syncthreads();
    }

    const long abase = (long)(m0 + wm + lm) * ldA + lq * 8;
    const long bbase = (long)(n0 + wn + lm) * ldB + lq * 8;

    const f32x4 zero = {0.f, 0.f, 0.f, 0.f};
    const u16x8 z8 = {0, 0, 0, 0, 0, 0, 0, 0};
    f32x4 acc[4][4];
    #pragma unroll
    for (int i = 0; i < 4; ++i)
        #pragma unroll
        for (int j = 0; j < 4; ++j) acc[i][j] = zero;

    int kb = 0, ke = K;
    if (MODE == 2) { kb = blockIdx.z * kchunk; ke = min(K, kb + kchunk); }
    // full steps: k0+32 <= K (uniform); at most one guarded tail step.
    const int kfull = (ke == K) ? (K & ~31) : ke;

    for (int k0 = kb; k0 < kfull; k0 += 32) {
        u16x8 av[4], bv[4];
        #pragma unroll
        for (int mi = 0; mi < 4; ++mi)
            av[mi] = *(const u16x8*)(Au + abase + (long)mi * 16 * ldA + k0);
        #pragma unroll
        for (int ni = 0; ni < 4; ++ni)
            bv[ni] = *(const u16x8*)(Bt + bbase + (long)ni * 16 * ldB + k0);
        #pragma unroll
        for (int mi = 0; mi < 4; ++mi)
            #pragma unroll
            for (int ni = 0; ni < 4; ++ni)
                acc[mi][ni] = __builtin_amdgcn_mfma_f32_16x16x32_bf16(
                    __builtin_bit_cast(bf16x8, av[mi]),
                    __builtin_bit_cast(bf16x8, bv[ni]), acc[mi][ni], 0, 0, 0);
    }
    if (kfull < ke) {            // K-tail (gemm1, dt==1: K=10000, 16 left)
        const int k0 = kfull;
        // a-load valid iff k0 + lq*8 + 8 <= K (x is NOT padded);
        // B (W1T) pad cols [K,10016) are zeros, so products vanish.
        const bool av_ok = (k0 + lq * 8 + 8) <= K;
        u16x8 av[4], bv[4];
        #pragma unroll
        for (int mi = 0; mi < 4; ++mi)
            av[mi] = av_ok ? *(const u16x8*)(Au + abase + (long)mi * 16 * ldA + k0)
                           : z8;
        #pragma unroll
        for (int ni = 0; ni < 4; ++ni)
            bv[ni] = *(const u16x8*)(Bt + bbase + (long)ni * 16 * ldB + k0);
        #pragma unroll
        for (int mi = 0; mi < 4; ++mi)
            #pragma unroll
            for (int ni = 0; ni < 4; ++ni)
                acc[mi][ni] = __builtin_amdgcn_mfma_f32_16x16x32_bf16(
                    __builtin_bit_cast(bf16x8, av[mi]),
                    __builtin_bit_cast(bf16x8, bv[ni]), acc[mi][ni], 0, 0, 0);
    }

    // epilogue. C/D layout: col = lane&15, row = (lane>>4)*4 + r  [m89/m91]
    if (MODE == 2) {
        float* dst = Cf + (long)blockIdx.z * M * (long)N;
        #pragma unroll
        for (int mi = 0; mi < 4; ++mi) {
            const int row0 = m0 + wm + mi * 16 + lq * 4;
            #pragma unroll
            for (int ni = 0; ni < 4; ++ni) {
                const int col = n0 + wn + ni * 16 + lm;
                #pragma unroll
                for (int r = 0; r < 4; ++r)
                    dst[(long)(row0 + r) * ldC + col] = acc[mi][ni][r];
            }
        }
    } else if (MODE == 0) {
        #pragma unroll
        for (int mi = 0; mi < 4; ++mi) {
            const int row0 = m0 + wm + mi * 16 + lq * 4;
            #pragma unroll
            for (int ni = 0; ni < 4; ++ni) {
                const int col = n0 + wn + ni * 16 + lm;
                const float bc = biasf[col];
                #pragma unroll
                for (int r = 0; r < 4; ++r) {
                    float v = acc[mi][ni][r] + bc;
                    ((u16*)Cb)[(long)(row0 + r) * ldC + col] = f2b(tanhf(v));
                }
            }
        }
    } else {
        #pragma unroll
        for (int mi = 0; mi < 4; ++mi) {
            const int row0 = m0 + wm + mi * 16 + lq * 4;
            #pragma unroll
            for (int ni = 0; ni < 4; ++ni) {
                const int col = n0 + wn + ni * 16 + lm;
                if (col < N) {
                    const float bc = biasf[col];
                    #pragma unroll
                    for (int r = 0; r < 4; ++r) {
                        float v = acc[mi][ni][r] + bc;
                        float fi = (v + 16.f) * 128.f + 0.5f;
                        int idx = (int)fi;
                        idx = idx < 0 ? 0 : (idx > 4095 ? 4095 : idx);
                        float y = lutS[idx] + 0.8f * v;
                        long off = (long)(row0 + r) * ldC + col;
                        float mk = dt ? b2f(((const u16*)mask)[off])
                                      : ((const float*)mask)[off];
                        float res = mk > 0.f ? y : v;
                        if (dt) ((u16*)Cb)[off] = f2b(res);
                        else    ((float*)Cb)[off] = res;
                    }
                }
            }
        }
    }
}

// reduce 7 split-K f32 partials + f32 bias, tanh -> bf16 h1. col = i & 511.
__global__ __launch_bounds__(256) void reduce_tanh7(const float* __restrict__ p,
        const float* __restrict__ biasf, u16* __restrict__ h, int MN) {
    int i = (blockIdx.x * 256 + threadIdx.x) * 4;
    if (i >= MN) return;
    f32x4 s = *(const f32x4*)(p + i);
    #pragma unroll
    for (int z = 1; z < 7; ++z) s += *(const f32x4*)(p + (long)z * MN + i);
    int col = i & 511;
    #pragma unroll
    for (int c = 0; c < 4; ++c)
        h[i + c] = f2b(tanhf(s[c] + biasf[col + c]));
}

extern "C" void kernel_launch(void* const* d_in, const int* in_sizes, int n_in,
                              void* d_out, int out_size, void* d_ws, size_t ws_size,
                              hipStream_t stream) {
    const void* x    = d_in[0];
    const void* mask = d_in[1];
    const void* W1   = d_in[2];
    const void* b1   = d_in[3];
    const void* W2   = d_in[4];
    const void* b2   = d_in[5];
    const void* W3   = d_in[6];
    const void* b3   = d_in[7];

    const int B = 4096, D = 10000, H = 512, KP = 10016;

    // d_out as scratch (all dead before gemm3's full overwrite).
    // bf16-out case (min d_out = 81.92 MB): used through h1 end = 73.70 MB.
    // f32-out case (163.84 MB): xb additionally at [73.70, 155.75) MB.
    char* ob = (char*)d_out;
    u16*   W1T     = (u16*)ob;                   // 512*10016*2  = 10,256,384
    u16*   W2T     = (u16*)(ob + 10256384);      // 512*512*2    =    524,288
    float* partial = (float*)(ob + 10780672);    // 7*4096*512*4 = 58,720,256
    u16*   h1      = (u16*)(ob + 69500928);      // 4096*512*2   =  4,194,304
    u16*   xb      = (u16*)(ob + 73695232);      // 4096*10016*2 = 82,051,072 (dt=0 only)

    // d_ws: live during gemm3 + setup data. 14.49 MB total.
    char* ws = (char*)d_ws;
    u16*   W3T   = (u16*)ws;                    // 10,240,000
    u16*   h2    = (u16*)(ws + 10240000);       //  4,194,304
    float* elut  = (float*)(ws + 14434304);     //     16,384
    float* canon = (float*)(ws + 14450688);     // 11,024*4 = 44,096
    float* b1f = canon, * b2f = canon + 512, * b3f = canon + 1024;

    // 1. all setup in one dispatch
    prep<<<14924, 256, 0, stream>>>(x, mask, W1, W2, W3, b1, b2, b3,
        d_in[8], d_in[9], d_in[10], d_in[11], d_in[12], d_in[13],
        W1T, W2T, W3T, xb, canon, elut);

    // 2. GEMM1 split-K=7: partial = x @ W1T^T (A/K selected by dt in-kernel)
    gemm_bt<2><<<dim3(32, 4, 7), 256, 0, stream>>>(xb, (const u16*)x, W1T,
        nullptr, nullptr, partial, mask, nullptr, B, H, KP, D, 1440, KP, H);

    // 3. reduce + bias + tanh -> h1
    reduce_tanh7<<<(B * H) / 1024, 256, 0, stream>>>(partial, b1f, h1, B * H);

    // 4. GEMM2: h2 = tanh(h1 @ W2T^T + b2)
    gemm_bt<0><<<dim3(32, 4), 256, 0, stream>>>(h1, h1, W2T, b2f, h2,
        nullptr, nullptr, nullptr, B, H, H, H, 0, H, H);

    // 5. GEMM3 + fused ENet/mask epilogue -> out (runtime out dtype)
    gemm_bt<1><<<dim3(32, 79), 256, 0, stream>>>(h2, h2, W3T, b3f, d_out,
        nullptr, mask, elut, B, D, H, H, 0, H, D);
}